// Round 12
// baseline (139.335 us; speedup 1.0000x reference)
//
#include <hip/hip_runtime.h>
#include <math.h>

// Problem sizes (fixed by the reference)
#define B   4
#define TQ  256
#define TV  1024
#define D   512
#define A   128

#define LOG2E     1.4426950408889634f
#define TWO_LOG2E 2.8853900817779268f
#define NEG_BIG_F (-1e9f)

#define QBLK (B * TQ / 8)   // 128 q-projection blocks
#define KBLK (B * TV / 8)   // 512 k-projection blocks

// ---------------------------------------------------------------------------
// Fused projection + exp(2x) for BOTH q and k.
//   q path: Eq[r, a]     = exp(2*(ctx[r,:]@Wq[:,a] + bq[a]))   [row-major]
//   k path: EkT[b, a, v] = exp(2*(inp[r,:]@Wk[:,a] + bk[a]))   [TRANSPOSED]
// Block = 512 thr (8 waves), 8 rows. d-split PER-WAVE 8 ways: wave g owns
// d in [g*64, g*64+64) -- wave-uniform by construction, so X reads stay
// scalar s_load_dwordx4. 640 blocks x 8 waves = 20 waves/CU (2x round 11),
// half the serial FMA chain per wave. Lane owns an a-pair x 8 rows = 16 acc.
// 8 wave partials reduced through 32 KB LDS.
// ---------------------------------------------------------------------------
__global__ __launch_bounds__(512, 4) void proj_exp_kernel(
    const float* __restrict__ ctx, const float* __restrict__ inp,
    const float* __restrict__ Wq, const float* __restrict__ bq,
    const float* __restrict__ Wk, const float* __restrict__ bk,
    float* __restrict__ Eq, float* __restrict__ EkT) {
  __shared__ float ps[8][8][A];     // 32 KB (row j, wave, a)
  __shared__ float es[A][9];        // 4.6 KB (transpose staging, +1 pad)

  bool isQ = blockIdx.x < QBLK;
  const float* X; const float* W; const float* bias; int r0;
  if (isQ) { X = ctx; W = Wq; bias = bq; r0 = blockIdx.x * 8; }
  else     { X = inp; W = Wk; bias = bk; r0 = (blockIdx.x - QBLK) * 8; }

  int tid = threadIdx.x;
  int ap = (tid & 63) * 2;      // a-pair base: 64 lanes cover a = 0..127
  int g  = tid >> 6;            // wave id 0..7  (wave-uniform)

  int dbase = __builtin_amdgcn_readfirstlane(g * 64);
  const float* Xr = X + (size_t)r0 * D + dbase;   // wave-uniform base
  const float* Wd = W + (size_t)dbase * A + ap;

  float2 acc[8];
#pragma unroll
  for (int j = 0; j < 8; ++j) acc[j] = make_float2(0.f, 0.f);

#pragma unroll 2
  for (int dd = 0; dd < 64; dd += 4) {
    float2 w0 = *(const float2*)(Wd + (size_t)(dd + 0) * A);
    float2 w1 = *(const float2*)(Wd + (size_t)(dd + 1) * A);
    float2 w2 = *(const float2*)(Wd + (size_t)(dd + 2) * A);
    float2 w3 = *(const float2*)(Wd + (size_t)(dd + 3) * A);
    float4 x[8];
#pragma unroll
    for (int j = 0; j < 8; ++j)
      x[j] = *(const float4*)(Xr + (size_t)j * D + dd);   // scalar s_load
#pragma unroll
    for (int j = 0; j < 8; ++j) {
      acc[j].x = fmaf(x[j].x, w0.x, acc[j].x);
      acc[j].y = fmaf(x[j].x, w0.y, acc[j].y);
      acc[j].x = fmaf(x[j].y, w1.x, acc[j].x);
      acc[j].y = fmaf(x[j].y, w1.y, acc[j].y);
      acc[j].x = fmaf(x[j].z, w2.x, acc[j].x);
      acc[j].y = fmaf(x[j].z, w2.y, acc[j].y);
      acc[j].x = fmaf(x[j].w, w3.x, acc[j].x);
      acc[j].y = fmaf(x[j].w, w3.y, acc[j].y);
    }
  }

  // write per-wave partials (each lane: 8 rows x its a-pair)
#pragma unroll
  for (int j = 0; j < 8; ++j)
    *(float2*)&ps[j][g][ap] = acc[j];
  __syncthreads();

  // finalize: thread -> (row j = tid>>6, a-pair a2); sum 8 partials + bias
  int j  = tid >> 6;            // 0..7
  int a2 = (tid & 63) * 2;
  float2 s = make_float2(0.f, 0.f);
#pragma unroll
  for (int gg = 0; gg < 8; ++gg) {
    float2 p = *(const float2*)&ps[j][gg][a2];
    s.x += p.x; s.y += p.y;
  }
  float2 bz = *(const float2*)(bias + a2);
  float2 ev;
  ev.x = __builtin_amdgcn_exp2f((s.x + bz.x) * TWO_LOG2E);
  ev.y = __builtin_amdgcn_exp2f((s.y + bz.y) * TWO_LOG2E);

  if (isQ) {
    *(float2*)(Eq + (size_t)(r0 + j) * A + a2) = ev;   // coalesced per row
  } else {
    es[a2 + 0][j] = ev.x;
    es[a2 + 1][j] = ev.y;
    __syncthreads();
    int b  = r0 >> 10;          // TV == 1024
    int v0 = r0 & (TV - 1);
    for (int i = tid; i < A * 8; i += 512) {
      int aa = i >> 3, jj = i & 7;
      EkT[((size_t)b * A + aa) * TV + v0 + jj] = es[aa][jj];
    }
  }
}

// ---------------------------------------------------------------------------
// Scores + softmax: TWO q rows per block, 512 threads (8 waves), 512 blocks
// -> 2 blocks/CU, 16 waves/CU. Thread owns 2 consecutive v for both rows:
// float2 EkT loads, 4 rcp chains, 4-batch software pipeline (8 in flight).
//   score[v] = sumV - 2 * sum_a v_a / (Eq[a]*EkT[a,v] + 1)
// ---------------------------------------------------------------------------
__global__ __launch_bounds__(512, 4) void score_softmax_kernel(
    const float* __restrict__ Eq, const float* __restrict__ EkT,
    const float* __restrict__ attn_v, const int* __restrict__ mask,
    float* __restrict__ attn) {
  __shared__ float redA[8], redB[8];
  __shared__ float bc[4];

  int tid = threadIdx.x;
  int v0  = (tid & 63) * 2 + (tid >> 6) * 128;  // wave-contiguous float2
  int r0  = blockIdx.x * 2;
  int b   = r0 >> 8;               // TQ == 256

  const float* eqA = Eq + (size_t)r0 * A;
  const float* eqB = eqA + A;

  float sumV = 0.f;
#pragma unroll 16
  for (int i = 0; i < A; ++i) sumV += attn_v[i];

  const float* ekb = EkT + (size_t)b * A * TV + v0;
  float2 tA = make_float2(0.f, 0.f);
  float2 tB = make_float2(0.f, 0.f);

  float2 c0 = *(const float2*)(ekb + (size_t)0 * TV);
  float2 c1 = *(const float2*)(ekb + (size_t)1 * TV);
  float2 c2 = *(const float2*)(ekb + (size_t)2 * TV);
  float2 c3 = *(const float2*)(ekb + (size_t)3 * TV);

  for (int i = 0; i < A; i += 4) {
    float2 n0, n1, n2, n3;
    if (i < A - 4) {
      n0 = *(const float2*)(ekb + (size_t)(i + 4) * TV);
      n1 = *(const float2*)(ekb + (size_t)(i + 5) * TV);
      n2 = *(const float2*)(ekb + (size_t)(i + 6) * TV);
      n3 = *(const float2*)(ekb + (size_t)(i + 7) * TV);
    }
    float av0 = attn_v[i + 0], av1 = attn_v[i + 1];
    float av2 = attn_v[i + 2], av3 = attn_v[i + 3];
    float qa0 = eqA[i + 0], qa1 = eqA[i + 1], qa2 = eqA[i + 2], qa3 = eqA[i + 3];
    float qb0 = eqB[i + 0], qb1 = eqB[i + 1], qb2 = eqB[i + 2], qb3 = eqB[i + 3];

    tA.x = fmaf(av0, __builtin_amdgcn_rcpf(fmaf(c0.x, qa0, 1.f)), tA.x);
    tA.y = fmaf(av0, __builtin_amdgcn_rcpf(fmaf(c0.y, qa0, 1.f)), tA.y);
    tB.x = fmaf(av0, __builtin_amdgcn_rcpf(fmaf(c0.x, qb0, 1.f)), tB.x);
    tB.y = fmaf(av0, __builtin_amdgcn_rcpf(fmaf(c0.y, qb0, 1.f)), tB.y);

    tA.x = fmaf(av1, __builtin_amdgcn_rcpf(fmaf(c1.x, qa1, 1.f)), tA.x);
    tA.y = fmaf(av1, __builtin_amdgcn_rcpf(fmaf(c1.y, qa1, 1.f)), tA.y);
    tB.x = fmaf(av1, __builtin_amdgcn_rcpf(fmaf(c1.x, qb1, 1.f)), tB.x);
    tB.y = fmaf(av1, __builtin_amdgcn_rcpf(fmaf(c1.y, qb1, 1.f)), tB.y);

    tA.x = fmaf(av2, __builtin_amdgcn_rcpf(fmaf(c2.x, qa2, 1.f)), tA.x);
    tA.y = fmaf(av2, __builtin_amdgcn_rcpf(fmaf(c2.y, qa2, 1.f)), tA.y);
    tB.x = fmaf(av2, __builtin_amdgcn_rcpf(fmaf(c2.x, qb2, 1.f)), tB.x);
    tB.y = fmaf(av2, __builtin_amdgcn_rcpf(fmaf(c2.y, qb2, 1.f)), tB.y);

    tA.x = fmaf(av3, __builtin_amdgcn_rcpf(fmaf(c3.x, qa3, 1.f)), tA.x);
    tA.y = fmaf(av3, __builtin_amdgcn_rcpf(fmaf(c3.y, qa3, 1.f)), tA.y);
    tB.x = fmaf(av3, __builtin_amdgcn_rcpf(fmaf(c3.x, qb3, 1.f)), tB.x);
    tB.y = fmaf(av3, __builtin_amdgcn_rcpf(fmaf(c3.y, qb3, 1.f)), tB.y);

    c0 = n0; c1 = n1; c2 = n2; c3 = n3;
  }

  int2 mk = *(const int2*)(mask + b * TV + v0);
  float mkx = (1.f - (float)mk.x) * NEG_BIG_F;
  float mky = (1.f - (float)mk.y) * NEG_BIG_F;
  float2 sA, sB;
  sA.x = sumV - 2.f * tA.x + mkx;
  sA.y = sumV - 2.f * tA.y + mky;
  sB.x = sumV - 2.f * tB.x + mkx;
  sB.y = sumV - 2.f * tB.y + mky;

  float mA = fmaxf(sA.x, sA.y);
  float mB = fmaxf(sB.x, sB.y);
  for (int off = 32; off > 0; off >>= 1) {
    mA = fmaxf(mA, __shfl_down(mA, off, 64));
    mB = fmaxf(mB, __shfl_down(mB, off, 64));
  }
  int w = tid >> 6;
  if ((tid & 63) == 0) { redA[w] = mA; redB[w] = mB; }
  __syncthreads();
  if (tid == 0) {
    float a = redA[0], bm = redB[0];
#pragma unroll
    for (int i = 1; i < 8; ++i) { a = fmaxf(a, redA[i]); bm = fmaxf(bm, redB[i]); }
    bc[0] = a; bc[1] = bm;
  }
  __syncthreads();
  float MA = bc[0], MB = bc[1];

  float2 eAv, eBv;
  eAv.x = __builtin_amdgcn_exp2f((sA.x - MA) * LOG2E);
  eAv.y = __builtin_amdgcn_exp2f((sA.y - MA) * LOG2E);
  eBv.x = __builtin_amdgcn_exp2f((sB.x - MB) * LOG2E);
  eBv.y = __builtin_amdgcn_exp2f((sB.y - MB) * LOG2E);
  float lA = eAv.x + eAv.y;
  float lB = eBv.x + eBv.y;
  for (int off = 32; off > 0; off >>= 1) {
    lA += __shfl_down(lA, off, 64);
    lB += __shfl_down(lB, off, 64);
  }
  __syncthreads();   // protect red[] before rewrite
  if ((tid & 63) == 0) { redA[w] = lA; redB[w] = lB; }
  __syncthreads();
  if (tid == 0) {
    float a = 0.f, bs = 0.f;
#pragma unroll
    for (int i = 0; i < 8; ++i) { a += redA[i]; bs += redB[i]; }
    bc[2] = a; bc[3] = bs;
  }
  __syncthreads();
  float iA = 1.f / bc[2];
  float iB = 1.f / bc[3];

  *(float2*)(attn + (size_t)r0 * TV + v0) =
      make_float2(eAv.x * iA, eAv.y * iA);
  *(float2*)(attn + (size_t)(r0 + 1) * TV + v0) =
      make_float2(eBv.x * iB, eBv.y * iB);
}

// ---------------------------------------------------------------------------
// out[b,q,:] = sum_v attn[b,q,v] * inputs[b,v,:]   -- NO ATOMICS.
// Round-8 structure + PREFETCH DISTANCE 2 (current batch + 2 in flight =
// 12 outstanding X loads/wave) to cover the ~250-cyc L2 latency that
// distance-1 left exposed. Block: 8 q x 128 d x full v; 8 waves own
// disjoint 128-v chunks; partials reduced through 32 KB LDS; coalesced
// store. grid (dt=4, qtile=128) = 512 blocks x 512 thr -> 16 waves/CU.
// ---------------------------------------------------------------------------
__global__ __launch_bounds__(512, 4) void pv_kernel(
    const float* __restrict__ attn, const float* __restrict__ X,
    float* __restrict__ out) {
  __shared__ float lds[8 * 1024];    // 32 KB: attn tile, then 8 partial tiles
  int dt = blockIdx.x;               // 0..3, d-slice of 128
  int q0 = blockIdx.y * 8;           // global row (b*TQ + q), 128 tiles
  int b  = q0 >> 8;                  // TQ == 256
  int tid  = threadIdx.x;
  int w    = tid >> 6;               // wave 0..7 -> v range [w*128, w*128+128)
  int lane = tid & 63;
  int col  = lane & 31;              // float4 d-column
  int qh   = lane >> 5;              // 0..1 -> q rows qh*4 .. qh*4+3
  int d0 = dt * 128 + col * 4;

  // stage attn tile: 8 rows x 1024 v (float4, coalesced)
  {
    const float4* src = (const float4*)(attn + (size_t)q0 * TV);
    float4* dst = (float4*)lds;
    for (int i = tid; i < 8 * 256; i += 512) dst[i] = src[i];
  }
  __syncthreads();

  float4 acc[4];
#pragma unroll
  for (int j = 0; j < 4; ++j) acc[j] = make_float4(0.f, 0.f, 0.f, 0.f);

  int vbase = w * 128;
  const float* Xb = X + ((size_t)b * TV + vbase) * D + d0;
  const float* arow = &lds[(qh * 4) * 1024 + vbase];  // 4 rows, stride 1024

  // prefetch distance 2: xc = batch vi, xm = batch vi+4
  float4 xc0 = *(const float4*)(Xb + (size_t)0 * D);
  float4 xc1 = *(const float4*)(Xb + (size_t)1 * D);
  float4 xc2 = *(const float4*)(Xb + (size_t)2 * D);
  float4 xc3 = *(const float4*)(Xb + (size_t)3 * D);
  float4 xm0 = *(const float4*)(Xb + (size_t)4 * D);
  float4 xm1 = *(const float4*)(Xb + (size_t)5 * D);
  float4 xm2 = *(const float4*)(Xb + (size_t)6 * D);
  float4 xm3 = *(const float4*)(Xb + (size_t)7 * D);

  for (int vi = 0; vi < 128; vi += 4) {
    float4 xn0, xn1, xn2, xn3;
    if (vi < 120) {
      const float* Xn = Xb + (size_t)(vi + 8) * D;
      xn0 = *(const float4*)(Xn + (size_t)0 * D);
      xn1 = *(const float4*)(Xn + (size_t)1 * D);
      xn2 = *(const float4*)(Xn + (size_t)2 * D);
      xn3 = *(const float4*)(Xn + (size_t)3 * D);
    }
#pragma unroll
    for (int j = 0; j < 4; ++j) {
      float4 av = *(const float4*)(arow + j * 1024 + vi);  // 2-addr bcast
      acc[j].x = fmaf(av.x, xc0.x, acc[j].x);
      acc[j].y = fmaf(av.x, xc0.y, acc[j].y);
      acc[j].z = fmaf(av.x, xc0.z, acc[j].z);
      acc[j].w = fmaf(av.x, xc0.w, acc[j].w);
      acc[j].x = fmaf(av.y, xc1.x, acc[j].x);
      acc[j].y = fmaf(av.y, xc1.y, acc[j].y);
      acc[j].z = fmaf(av.y, xc1.z, acc[j].z);
      acc[j].w = fmaf(av.y, xc1.w, acc[j].w);
      acc[j].x = fmaf(av.z, xc2.x, acc[j].x);
      acc[j].y = fmaf(av.z, xc2.y, acc[j].y);
      acc[j].z = fmaf(av.z, xc2.z, acc[j].z);
      acc[j].w = fmaf(av.z, xc2.w, acc[j].w);
      acc[j].x = fmaf(av.w, xc3.x, acc[j].x);
      acc[j].y = fmaf(av.w, xc3.y, acc[j].y);
      acc[j].z = fmaf(av.w, xc3.z, acc[j].z);
      acc[j].w = fmaf(av.w, xc3.w, acc[j].w);
    }
    xc0 = xm0; xc1 = xm1; xc2 = xm2; xc3 = xm3;
    xm0 = xn0; xm1 = xn1; xm2 = xn2; xm3 = xn3;
  }

  __syncthreads();   // everyone done READING the attn tile

  // write wave partials: lds[w][8 rows][32 float4 cols]
  {
    float4* pat = (float4*)lds + (size_t)w * 256;
#pragma unroll
    for (int j = 0; j < 4; ++j)
      pat[(qh * 4 + j) * 32 + col] = acc[j];
  }
  __syncthreads();

  // reduce 8 partials and store: 256 float4 outputs
  if (tid < 256) {
    int row = tid >> 5;            // 0..7
    int c   = tid & 31;            // 0..31
    const float4* p = (const float4*)lds + tid;  // == row*32 + c
    float4 r = p[0];
#pragma unroll
    for (int i = 1; i < 8; ++i) {
      float4 t = p[(size_t)i * 256];
      r.x += t.x; r.y += t.y; r.z += t.z; r.w += t.w;
    }
    *(float4*)(out + (size_t)(q0 + row) * D + dt * 128 + c * 4) = r;
  }
}

extern "C" void kernel_launch(void* const* d_in, const int* in_sizes, int n_in,
                              void* d_out, int out_size, void* d_ws, size_t ws_size,
                              hipStream_t stream) {
  const float* inputs  = (const float*)d_in[0];  // [B,TV,D]
  const float* context = (const float*)d_in[1];  // [B,TQ,D]
  const int*   mask    = (const int*)d_in[2];    // [B,TV]
  const float* Wk      = (const float*)d_in[3];  // [D,A]
  const float* bk      = (const float*)d_in[4];  // [A]
  const float* Wq      = (const float*)d_in[5];  // [D,A]
  const float* bq      = (const float*)d_in[6];  // [A]
  const float* attn_v  = (const float*)d_in[7];  // [A]
  float* out = (float*)d_out;                    // [B,TQ,D]

  // Workspace layout (fp32): Eq | EkT | attn  = 0.5MB + 2MB + 4MB
  float* Eq   = (float*)d_ws;             // [B*TQ, A]
  float* EkT  = Eq + B * TQ * A;          // [B, A, TV]  (transposed!)
  float* attn = EkT + (size_t)B * A * TV; // [B*TQ, TV]

  proj_exp_kernel<<<QBLK + KBLK, 512, 0, stream>>>(context, inputs, Wq, bq,
                                                   Wk, bk, Eq, EkT);
  score_softmax_kernel<<<B * TQ / 2, 512, 0, stream>>>(Eq, EkT, attn_v, mask,
                                                       attn);
  pv_kernel<<<dim3(4, 128), 512, 0, stream>>>(attn, inputs, out);
}

// Round 13
// 137.257 us; speedup vs baseline: 1.0151x; 1.0151x over previous
//
#include <hip/hip_runtime.h>
#include <math.h>

// Problem sizes (fixed by the reference)
#define B   4
#define TQ  256
#define TV  1024
#define D   512
#define A   128

#define LOG2E     1.4426950408889634f
#define TWO_LOG2E 2.8853900817779268f
#define NEG_BIG_F (-1e9f)

#define QBLK (B * TQ / 8)   // 128 q-projection blocks
#define KBLK (B * TV / 8)   // 512 k-projection blocks

// ---------------------------------------------------------------------------
// Fused projection + exp(2x) for BOTH q and k.  (round-11 best config)
//   q path: Eq[r, a]     = exp(2*(ctx[r,:]@Wq[:,a] + bq[a]))   [row-major]
//   k path: EkT[b, a, v] = exp(2*(inp[r,:]@Wk[:,a] + bk[a]))   [TRANSPOSED]
// Block = 256 thr (4 waves). d-split PER-WAVE (g = tid>>6, wave-uniform by
// construction): wave g owns d in [g*128, g*128+128). All 64 lanes share X
// addresses -> s_load_dwordx4. Lane owns an a-pair x 8 rows = 16 acc.
// ---------------------------------------------------------------------------
__global__ __launch_bounds__(256, 4) void proj_exp_kernel(
    const float* __restrict__ ctx, const float* __restrict__ inp,
    const float* __restrict__ Wq, const float* __restrict__ bq,
    const float* __restrict__ Wk, const float* __restrict__ bk,
    float* __restrict__ Eq, float* __restrict__ EkT) {
  __shared__ float ps[8][4][A];     // 16 KB (row j, wave, a)
  __shared__ float es[A][9];        // 4.6 KB (transpose staging, +1 pad)

  bool isQ = blockIdx.x < QBLK;
  const float* X; const float* W; const float* bias; int r0;
  if (isQ) { X = ctx; W = Wq; bias = bq; r0 = blockIdx.x * 8; }
  else     { X = inp; W = Wk; bias = bk; r0 = (blockIdx.x - QBLK) * 8; }

  int tid = threadIdx.x;
  int ap = (tid & 63) * 2;      // a-pair base: 64 lanes cover a = 0..127
  int g  = tid >> 6;            // wave id 0..3  (wave-uniform)

  int dbase = __builtin_amdgcn_readfirstlane(g * 128);
  const float* Xr = X + (size_t)r0 * D + dbase;   // wave-uniform base
  const float* Wd = W + (size_t)dbase * A + ap;

  float2 acc[8];
#pragma unroll
  for (int j = 0; j < 8; ++j) acc[j] = make_float2(0.f, 0.f);

#pragma unroll 2
  for (int dd = 0; dd < 128; dd += 4) {
    float2 w0 = *(const float2*)(Wd + (size_t)(dd + 0) * A);
    float2 w1 = *(const float2*)(Wd + (size_t)(dd + 1) * A);
    float2 w2 = *(const float2*)(Wd + (size_t)(dd + 2) * A);
    float2 w3 = *(const float2*)(Wd + (size_t)(dd + 3) * A);
    float4 x[8];
#pragma unroll
    for (int j = 0; j < 8; ++j)
      x[j] = *(const float4*)(Xr + (size_t)j * D + dd);   // scalar s_load
#pragma unroll
    for (int j = 0; j < 8; ++j) {
      acc[j].x = fmaf(x[j].x, w0.x, acc[j].x);
      acc[j].y = fmaf(x[j].x, w0.y, acc[j].y);
      acc[j].x = fmaf(x[j].y, w1.x, acc[j].x);
      acc[j].y = fmaf(x[j].y, w1.y, acc[j].y);
      acc[j].x = fmaf(x[j].z, w2.x, acc[j].x);
      acc[j].y = fmaf(x[j].z, w2.y, acc[j].y);
      acc[j].x = fmaf(x[j].w, w3.x, acc[j].x);
      acc[j].y = fmaf(x[j].w, w3.y, acc[j].y);
    }
  }

#pragma unroll
  for (int j = 0; j < 8; ++j)
    *(float2*)&ps[j][g][ap] = acc[j];
  __syncthreads();

  int j  = tid >> 5;            // 0..7
  int a4 = (tid & 31) * 4;
  float4 p0 = *(const float4*)&ps[j][0][a4];
  float4 p1 = *(const float4*)&ps[j][1][a4];
  float4 p2 = *(const float4*)&ps[j][2][a4];
  float4 p3 = *(const float4*)&ps[j][3][a4];
  float4 bz = *(const float4*)(bias + a4);
  float4 ev;
  ev.x = __builtin_amdgcn_exp2f((((p0.x + p1.x) + (p2.x + p3.x)) + bz.x) * TWO_LOG2E);
  ev.y = __builtin_amdgcn_exp2f((((p0.y + p1.y) + (p2.y + p3.y)) + bz.y) * TWO_LOG2E);
  ev.z = __builtin_amdgcn_exp2f((((p0.z + p1.z) + (p2.z + p3.z)) + bz.z) * TWO_LOG2E);
  ev.w = __builtin_amdgcn_exp2f((((p0.w + p1.w) + (p2.w + p3.w)) + bz.w) * TWO_LOG2E);

  if (isQ) {
    *(float4*)(Eq + (size_t)(r0 + j) * A + a4) = ev;   // coalesced per row
  } else {
    es[a4 + 0][j] = ev.x;
    es[a4 + 1][j] = ev.y;
    es[a4 + 2][j] = ev.z;
    es[a4 + 3][j] = ev.w;
    __syncthreads();
    int b  = r0 >> 10;          // TV == 1024
    int v0 = r0 & (TV - 1);
    for (int i = tid; i < A * 8; i += 256) {
      int aa = i >> 3, jj = i & 7;
      EkT[((size_t)b * A + aa) * TV + v0 + jj] = es[aa][jj];
    }
  }
}

// ---------------------------------------------------------------------------
// Scores + softmax (round-11 best config): TWO q rows per block, 512 threads
// (8 waves), 512 blocks -> 16 waves/CU. Thread owns 2 v for both rows:
// float2 EkT loads, 4 rcp chains, 4-batch software pipeline (8 in flight).
//   score[v] = sumV - 2 * sum_a v_a / (Eq[a]*EkT[a,v] + 1)
// ---------------------------------------------------------------------------
__global__ __launch_bounds__(512, 4) void score_softmax_kernel(
    const float* __restrict__ Eq, const float* __restrict__ EkT,
    const float* __restrict__ attn_v, const int* __restrict__ mask,
    float* __restrict__ attn) {
  __shared__ float redA[8], redB[8];
  __shared__ float bc[4];

  int tid = threadIdx.x;
  int v0  = (tid & 63) * 2 + (tid >> 6) * 128;  // wave-contiguous float2
  int r0  = blockIdx.x * 2;
  int b   = r0 >> 8;               // TQ == 256

  const float* eqA = Eq + (size_t)r0 * A;
  const float* eqB = eqA + A;

  float sumV = 0.f;
#pragma unroll 16
  for (int i = 0; i < A; ++i) sumV += attn_v[i];

  const float* ekb = EkT + (size_t)b * A * TV + v0;
  float2 tA = make_float2(0.f, 0.f);
  float2 tB = make_float2(0.f, 0.f);

  float2 c0 = *(const float2*)(ekb + (size_t)0 * TV);
  float2 c1 = *(const float2*)(ekb + (size_t)1 * TV);
  float2 c2 = *(const float2*)(ekb + (size_t)2 * TV);
  float2 c3 = *(const float2*)(ekb + (size_t)3 * TV);

  for (int i = 0; i < A; i += 4) {
    float2 n0, n1, n2, n3;
    if (i < A - 4) {
      n0 = *(const float2*)(ekb + (size_t)(i + 4) * TV);
      n1 = *(const float2*)(ekb + (size_t)(i + 5) * TV);
      n2 = *(const float2*)(ekb + (size_t)(i + 6) * TV);
      n3 = *(const float2*)(ekb + (size_t)(i + 7) * TV);
    }
    float av0 = attn_v[i + 0], av1 = attn_v[i + 1];
    float av2 = attn_v[i + 2], av3 = attn_v[i + 3];
    float qa0 = eqA[i + 0], qa1 = eqA[i + 1], qa2 = eqA[i + 2], qa3 = eqA[i + 3];
    float qb0 = eqB[i + 0], qb1 = eqB[i + 1], qb2 = eqB[i + 2], qb3 = eqB[i + 3];

    tA.x = fmaf(av0, __builtin_amdgcn_rcpf(fmaf(c0.x, qa0, 1.f)), tA.x);
    tA.y = fmaf(av0, __builtin_amdgcn_rcpf(fmaf(c0.y, qa0, 1.f)), tA.y);
    tB.x = fmaf(av0, __builtin_amdgcn_rcpf(fmaf(c0.x, qb0, 1.f)), tB.x);
    tB.y = fmaf(av0, __builtin_amdgcn_rcpf(fmaf(c0.y, qb0, 1.f)), tB.y);

    tA.x = fmaf(av1, __builtin_amdgcn_rcpf(fmaf(c1.x, qa1, 1.f)), tA.x);
    tA.y = fmaf(av1, __builtin_amdgcn_rcpf(fmaf(c1.y, qa1, 1.f)), tA.y);
    tB.x = fmaf(av1, __builtin_amdgcn_rcpf(fmaf(c1.x, qb1, 1.f)), tB.x);
    tB.y = fmaf(av1, __builtin_amdgcn_rcpf(fmaf(c1.y, qb1, 1.f)), tB.y);

    tA.x = fmaf(av2, __builtin_amdgcn_rcpf(fmaf(c2.x, qa2, 1.f)), tA.x);
    tA.y = fmaf(av2, __builtin_amdgcn_rcpf(fmaf(c2.y, qa2, 1.f)), tA.y);
    tB.x = fmaf(av2, __builtin_amdgcn_rcpf(fmaf(c2.x, qb2, 1.f)), tB.x);
    tB.y = fmaf(av2, __builtin_amdgcn_rcpf(fmaf(c2.y, qb2, 1.f)), tB.y);

    tA.x = fmaf(av3, __builtin_amdgcn_rcpf(fmaf(c3.x, qa3, 1.f)), tA.x);
    tA.y = fmaf(av3, __builtin_amdgcn_rcpf(fmaf(c3.y, qa3, 1.f)), tA.y);
    tB.x = fmaf(av3, __builtin_amdgcn_rcpf(fmaf(c3.x, qb3, 1.f)), tB.x);
    tB.y = fmaf(av3, __builtin_amdgcn_rcpf(fmaf(c3.y, qb3, 1.f)), tB.y);

    c0 = n0; c1 = n1; c2 = n2; c3 = n3;
  }

  int2 mk = *(const int2*)(mask + b * TV + v0);
  float mkx = (1.f - (float)mk.x) * NEG_BIG_F;
  float mky = (1.f - (float)mk.y) * NEG_BIG_F;
  float2 sA, sB;
  sA.x = sumV - 2.f * tA.x + mkx;
  sA.y = sumV - 2.f * tA.y + mky;
  sB.x = sumV - 2.f * tB.x + mkx;
  sB.y = sumV - 2.f * tB.y + mky;

  float mA = fmaxf(sA.x, sA.y);
  float mB = fmaxf(sB.x, sB.y);
  for (int off = 32; off > 0; off >>= 1) {
    mA = fmaxf(mA, __shfl_down(mA, off, 64));
    mB = fmaxf(mB, __shfl_down(mB, off, 64));
  }
  int w = tid >> 6;
  if ((tid & 63) == 0) { redA[w] = mA; redB[w] = mB; }
  __syncthreads();
  if (tid == 0) {
    float a = redA[0], bm = redB[0];
#pragma unroll
    for (int i = 1; i < 8; ++i) { a = fmaxf(a, redA[i]); bm = fmaxf(bm, redB[i]); }
    bc[0] = a; bc[1] = bm;
  }
  __syncthreads();
  float MA = bc[0], MB = bc[1];

  float2 eAv, eBv;
  eAv.x = __builtin_amdgcn_exp2f((sA.x - MA) * LOG2E);
  eAv.y = __builtin_amdgcn_exp2f((sA.y - MA) * LOG2E);
  eBv.x = __builtin_amdgcn_exp2f((sB.x - MB) * LOG2E);
  eBv.y = __builtin_amdgcn_exp2f((sB.y - MB) * LOG2E);
  float lA = eAv.x + eAv.y;
  float lB = eBv.x + eBv.y;
  for (int off = 32; off > 0; off >>= 1) {
    lA += __shfl_down(lA, off, 64);
    lB += __shfl_down(lB, off, 64);
  }
  __syncthreads();   // protect red[] before rewrite
  if ((tid & 63) == 0) { redA[w] = lA; redB[w] = lB; }
  __syncthreads();
  if (tid == 0) {
    float a = 0.f, bs = 0.f;
#pragma unroll
    for (int i = 0; i < 8; ++i) { a += redA[i]; bs += redB[i]; }
    bc[2] = a; bc[3] = bs;
  }
  __syncthreads();
  float iA = 1.f / bc[2];
  float iB = 1.f / bc[3];

  *(float2*)(attn + (size_t)r0 * TV + v0) =
      make_float2(eAv.x * iA, eAv.y * iA);
  *(float2*)(attn + (size_t)(r0 + 1) * TV + v0) =
      make_float2(eBv.x * iB, eBv.y * iB);
}

// ---------------------------------------------------------------------------
// out[b,q,:] = sum_v attn[b,q,v] * inputs[b,v,:]   -- NO LDS IN HOT LOOP.
// attn[q][v] is lane-invariant: with q,v wave-uniform (qr/vch forced to
// SGPR via readfirstlane -- legal, wave-uniform by construction), attn reads
// compile to s_load_dwordx4 on the scalar pipe. X per-lane float4, 64 lanes
// x 16B = 1KB coalesced, zero duplication. 64 FMA per 4 VMEM. LDS only for
// the final 4-way vchunk reduction (32 KB).
// Wave = 4 q-rows x 256 d x 256 v; block = 8 waves = 8q x 256d x 1024v.
// grid (dt=2, qt=128) = 256 blocks x 512 thr.
// ---------------------------------------------------------------------------
__global__ __launch_bounds__(512, 4) void pv_kernel(
    const float* __restrict__ attn, const float* __restrict__ X,
    float* __restrict__ out) {
  __shared__ float4 ps[4][8][64];    // 32 KB: [vchunk][q row][64 d-cols f4]
  int dt = blockIdx.x;               // 0..1, d-slice of 256
  int q0 = blockIdx.y * 8;           // global row (b*TQ + q), 128 tiles
  int b  = q0 >> 8;                  // TQ == 256
  int tid  = threadIdx.x;
  int w    = tid >> 6;               // wave 0..7
  int lane = tid & 63;
  int qr  = __builtin_amdgcn_readfirstlane((w & 1) * 4);  // 4 q rows
  int vch = __builtin_amdgcn_readfirstlane(w >> 1);       // v-chunk 0..3
  int d0 = dt * 256 + lane * 4;

  const float* Xb   = X + ((size_t)b * TV + vch * 256) * D + d0;
  const float* arow = attn + (size_t)(q0 + qr) * TV + vch * 256; // uniform

  float4 acc[4];
#pragma unroll
  for (int j = 0; j < 4; ++j) acc[j] = make_float4(0.f, 0.f, 0.f, 0.f);

  // prefetch unit 0: 4 X rows (per-lane) + 4 attn quads (scalar)
  float4 xc0 = *(const float4*)(Xb + (size_t)0 * D);
  float4 xc1 = *(const float4*)(Xb + (size_t)1 * D);
  float4 xc2 = *(const float4*)(Xb + (size_t)2 * D);
  float4 xc3 = *(const float4*)(Xb + (size_t)3 * D);
  float4 ac0 = *(const float4*)(arow + (size_t)0 * TV);
  float4 ac1 = *(const float4*)(arow + (size_t)1 * TV);
  float4 ac2 = *(const float4*)(arow + (size_t)2 * TV);
  float4 ac3 = *(const float4*)(arow + (size_t)3 * TV);

  for (int vi = 0; vi < 256; vi += 4) {
    float4 xn0, xn1, xn2, xn3, an0, an1, an2, an3;
    if (vi < 252) {
      const float* Xn = Xb + (size_t)(vi + 4) * D;
      xn0 = *(const float4*)(Xn + (size_t)0 * D);
      xn1 = *(const float4*)(Xn + (size_t)1 * D);
      xn2 = *(const float4*)(Xn + (size_t)2 * D);
      xn3 = *(const float4*)(Xn + (size_t)3 * D);
      an0 = *(const float4*)(arow + (size_t)0 * TV + vi + 4);
      an1 = *(const float4*)(arow + (size_t)1 * TV + vi + 4);
      an2 = *(const float4*)(arow + (size_t)2 * TV + vi + 4);
      an3 = *(const float4*)(arow + (size_t)3 * TV + vi + 4);
    }
    // 4 q rows x 4 v x 4 d = 64 FMA
#pragma unroll
    for (int j = 0; j < 4; ++j) {
      float4 a = (j == 0) ? ac0 : (j == 1) ? ac1 : (j == 2) ? ac2 : ac3;
      acc[j].x = fmaf(a.x, xc0.x, acc[j].x);
      acc[j].y = fmaf(a.x, xc0.y, acc[j].y);
      acc[j].z = fmaf(a.x, xc0.z, acc[j].z);
      acc[j].w = fmaf(a.x, xc0.w, acc[j].w);
      acc[j].x = fmaf(a.y, xc1.x, acc[j].x);
      acc[j].y = fmaf(a.y, xc1.y, acc[j].y);
      acc[j].z = fmaf(a.y, xc1.z, acc[j].z);
      acc[j].w = fmaf(a.y, xc1.w, acc[j].w);
      acc[j].x = fmaf(a.z, xc2.x, acc[j].x);
      acc[j].y = fmaf(a.z, xc2.y, acc[j].y);
      acc[j].z = fmaf(a.z, xc2.z, acc[j].z);
      acc[j].w = fmaf(a.z, xc2.w, acc[j].w);
      acc[j].x = fmaf(a.w, xc3.x, acc[j].x);
      acc[j].y = fmaf(a.w, xc3.y, acc[j].y);
      acc[j].z = fmaf(a.w, xc3.z, acc[j].z);
      acc[j].w = fmaf(a.w, xc3.w, acc[j].w);
    }
    xc0 = xn0; xc1 = xn1; xc2 = xn2; xc3 = xn3;
    ac0 = an0; ac1 = an1; ac2 = an2; ac3 = an3;
  }

  // write wave partials and reduce over 4 v-chunks
#pragma unroll
  for (int j = 0; j < 4; ++j)
    ps[vch][qr + j][lane] = acc[j];
  __syncthreads();

  {
    int row = tid >> 6;            // 0..7
    int c   = tid & 63;            // 0..63
    float4 r0v = ps[0][row][c];
    float4 r1v = ps[1][row][c];
    float4 r2v = ps[2][row][c];
    float4 r3v = ps[3][row][c];
    float4 r;
    r.x = (r0v.x + r1v.x) + (r2v.x + r3v.x);
    r.y = (r0v.y + r1v.y) + (r2v.y + r3v.y);
    r.z = (r0v.z + r1v.z) + (r2v.z + r3v.z);
    r.w = (r0v.w + r1v.w) + (r2v.w + r3v.w);
    *(float4*)(out + (size_t)(q0 + row) * D + dt * 256 + c * 4) = r;
  }
}

extern "C" void kernel_launch(void* const* d_in, const int* in_sizes, int n_in,
                              void* d_out, int out_size, void* d_ws, size_t ws_size,
                              hipStream_t stream) {
  const float* inputs  = (const float*)d_in[0];  // [B,TV,D]
  const float* context = (const float*)d_in[1];  // [B,TQ,D]
  const int*   mask    = (const int*)d_in[2];    // [B,TV]
  const float* Wk      = (const float*)d_in[3];  // [D,A]
  const float* bk      = (const float*)d_in[4];  // [A]
  const float* Wq      = (const float*)d_in[5];  // [D,A]
  const float* bq      = (const float*)d_in[6];  // [A]
  const float* attn_v  = (const float*)d_in[7];  // [A]
  float* out = (float*)d_out;                    // [B,TQ,D]

  // Workspace layout (fp32): Eq | EkT | attn  = 0.5MB + 2MB + 4MB
  float* Eq   = (float*)d_ws;             // [B*TQ, A]
  float* EkT  = Eq + B * TQ * A;          // [B, A, TV]  (transposed!)
  float* attn = EkT + (size_t)B * A * TV; // [B*TQ, TV]

  proj_exp_kernel<<<QBLK + KBLK, 256, 0, stream>>>(context, inputs, Wq, bq,
                                                   Wk, bk, Eq, EkT);
  score_softmax_kernel<<<B * TQ / 2, 512, 0, stream>>>(Eq, EkT, attn_v, mask,
                                                       attn);
  pv_kernel<<<dim3(2, 128), 512, 0, stream>>>(attn, inputs, out);
}

// Round 14
// 134.016 us; speedup vs baseline: 1.0397x; 1.0242x over previous
//
#include <hip/hip_runtime.h>
#include <math.h>

// Problem sizes (fixed by the reference)
#define B   4
#define TQ  256
#define TV  1024
#define D   512
#define A   128

#define LOG2E     1.4426950408889634f
#define TWO_LOG2E 2.8853900817779268f
#define NEG_BIG_F (-1e9f)

#define QBLK (B * TQ / 8)   // 128 q-projection blocks
#define KBLK (B * TV / 8)   // 512 k-projection blocks

// ---------------------------------------------------------------------------
// Fused projection + exp(2x) for BOTH q and k.  (round-11 best config)
//   q path: Eq[r, a]     = exp(2*(ctx[r,:]@Wq[:,a] + bq[a]))   [row-major]
//   k path: EkT[b, a, v] = exp(2*(inp[r,:]@Wk[:,a] + bk[a]))   [TRANSPOSED]
// Block = 256 thr (4 waves). d-split PER-WAVE (g = tid>>6, wave-uniform by
// construction): wave g owns d in [g*128, g*128+128). All 64 lanes share X
// addresses -> s_load_dwordx4. Lane owns an a-pair x 8 rows = 16 acc.
// ---------------------------------------------------------------------------
__global__ __launch_bounds__(256, 4) void proj_exp_kernel(
    const float* __restrict__ ctx, const float* __restrict__ inp,
    const float* __restrict__ Wq, const float* __restrict__ bq,
    const float* __restrict__ Wk, const float* __restrict__ bk,
    float* __restrict__ Eq, float* __restrict__ EkT) {
  __shared__ float ps[8][4][A];     // 16 KB (row j, wave, a)
  __shared__ float es[A][9];        // 4.6 KB (transpose staging, +1 pad)

  bool isQ = blockIdx.x < QBLK;
  const float* X; const float* W; const float* bias; int r0;
  if (isQ) { X = ctx; W = Wq; bias = bq; r0 = blockIdx.x * 8; }
  else     { X = inp; W = Wk; bias = bk; r0 = (blockIdx.x - QBLK) * 8; }

  int tid = threadIdx.x;
  int ap = (tid & 63) * 2;      // a-pair base: 64 lanes cover a = 0..127
  int g  = tid >> 6;            // wave id 0..3  (wave-uniform)

  int dbase = __builtin_amdgcn_readfirstlane(g * 128);
  const float* Xr = X + (size_t)r0 * D + dbase;   // wave-uniform base
  const float* Wd = W + (size_t)dbase * A + ap;

  float2 acc[8];
#pragma unroll
  for (int j = 0; j < 8; ++j) acc[j] = make_float2(0.f, 0.f);

#pragma unroll 2
  for (int dd = 0; dd < 128; dd += 4) {
    float2 w0 = *(const float2*)(Wd + (size_t)(dd + 0) * A);
    float2 w1 = *(const float2*)(Wd + (size_t)(dd + 1) * A);
    float2 w2 = *(const float2*)(Wd + (size_t)(dd + 2) * A);
    float2 w3 = *(const float2*)(Wd + (size_t)(dd + 3) * A);
    float4 x[8];
#pragma unroll
    for (int j = 0; j < 8; ++j)
      x[j] = *(const float4*)(Xr + (size_t)j * D + dd);   // scalar s_load
#pragma unroll
    for (int j = 0; j < 8; ++j) {
      acc[j].x = fmaf(x[j].x, w0.x, acc[j].x);
      acc[j].y = fmaf(x[j].x, w0.y, acc[j].y);
      acc[j].x = fmaf(x[j].y, w1.x, acc[j].x);
      acc[j].y = fmaf(x[j].y, w1.y, acc[j].y);
      acc[j].x = fmaf(x[j].z, w2.x, acc[j].x);
      acc[j].y = fmaf(x[j].z, w2.y, acc[j].y);
      acc[j].x = fmaf(x[j].w, w3.x, acc[j].x);
      acc[j].y = fmaf(x[j].w, w3.y, acc[j].y);
    }
  }

#pragma unroll
  for (int j = 0; j < 8; ++j)
    *(float2*)&ps[j][g][ap] = acc[j];
  __syncthreads();

  int j  = tid >> 5;            // 0..7
  int a4 = (tid & 31) * 4;
  float4 p0 = *(const float4*)&ps[j][0][a4];
  float4 p1 = *(const float4*)&ps[j][1][a4];
  float4 p2 = *(const float4*)&ps[j][2][a4];
  float4 p3 = *(const float4*)&ps[j][3][a4];
  float4 bz = *(const float4*)(bias + a4);
  float4 ev;
  ev.x = __builtin_amdgcn_exp2f((((p0.x + p1.x) + (p2.x + p3.x)) + bz.x) * TWO_LOG2E);
  ev.y = __builtin_amdgcn_exp2f((((p0.y + p1.y) + (p2.y + p3.y)) + bz.y) * TWO_LOG2E);
  ev.z = __builtin_amdgcn_exp2f((((p0.z + p1.z) + (p2.z + p3.z)) + bz.z) * TWO_LOG2E);
  ev.w = __builtin_amdgcn_exp2f((((p0.w + p1.w) + (p2.w + p3.w)) + bz.w) * TWO_LOG2E);

  if (isQ) {
    *(float4*)(Eq + (size_t)(r0 + j) * A + a4) = ev;   // coalesced per row
  } else {
    es[a4 + 0][j] = ev.x;
    es[a4 + 1][j] = ev.y;
    es[a4 + 2][j] = ev.z;
    es[a4 + 3][j] = ev.w;
    __syncthreads();
    int b  = r0 >> 10;          // TV == 1024
    int v0 = r0 & (TV - 1);
    for (int i = tid; i < A * 8; i += 256) {
      int aa = i >> 3, jj = i & 7;
      EkT[((size_t)b * A + aa) * TV + v0 + jj] = es[aa][jj];
    }
  }
}

// ---------------------------------------------------------------------------
// Scores + softmax (round-11 kernel, XCD-SWIZZLED block map): TWO q rows per
// block, 512 threads (8 waves), 512 blocks -> 16 waves/CU.
// Block map: b = blockIdx&3 (ties batch to XCD via round-robin dispatch so
// each XCD's 4MB L2 caches exactly one 2MB EkT[b] slice); pair index from
// the remaining bits.
//   score[v] = sumV - 2 * sum_a v_a / (Eq[a]*EkT[a,v] + 1)
// ---------------------------------------------------------------------------
__global__ __launch_bounds__(512, 4) void score_softmax_kernel(
    const float* __restrict__ Eq, const float* __restrict__ EkT,
    const float* __restrict__ attn_v, const int* __restrict__ mask,
    float* __restrict__ attn) {
  __shared__ float redA[8], redB[8];
  __shared__ float bc[4];

  int tid = threadIdx.x;
  int v0  = (tid & 63) * 2 + (tid >> 6) * 128;  // wave-contiguous float2
  // XCD-aware decomposition: xcd = blk&7 -> b = xcd&3; pair = (xcd>>2)*64+grp
  int xcd = blockIdx.x & 7;
  int grp = blockIdx.x >> 3;           // 0..63
  int b   = xcd & 3;
  int pair = (xcd >> 2) * 64 + grp;    // 0..127
  int r0  = b * TQ + pair * 2;

  const float* eqA = Eq + (size_t)r0 * A;
  const float* eqB = eqA + A;

  float sumV = 0.f;
#pragma unroll 16
  for (int i = 0; i < A; ++i) sumV += attn_v[i];

  const float* ekb = EkT + (size_t)b * A * TV + v0;
  float2 tA = make_float2(0.f, 0.f);
  float2 tB = make_float2(0.f, 0.f);

  float2 c0 = *(const float2*)(ekb + (size_t)0 * TV);
  float2 c1 = *(const float2*)(ekb + (size_t)1 * TV);
  float2 c2 = *(const float2*)(ekb + (size_t)2 * TV);
  float2 c3 = *(const float2*)(ekb + (size_t)3 * TV);

  for (int i = 0; i < A; i += 4) {
    float2 n0, n1, n2, n3;
    if (i < A - 4) {
      n0 = *(const float2*)(ekb + (size_t)(i + 4) * TV);
      n1 = *(const float2*)(ekb + (size_t)(i + 5) * TV);
      n2 = *(const float2*)(ekb + (size_t)(i + 6) * TV);
      n3 = *(const float2*)(ekb + (size_t)(i + 7) * TV);
    }
    float av0 = attn_v[i + 0], av1 = attn_v[i + 1];
    float av2 = attn_v[i + 2], av3 = attn_v[i + 3];
    float qa0 = eqA[i + 0], qa1 = eqA[i + 1], qa2 = eqA[i + 2], qa3 = eqA[i + 3];
    float qb0 = eqB[i + 0], qb1 = eqB[i + 1], qb2 = eqB[i + 2], qb3 = eqB[i + 3];

    tA.x = fmaf(av0, __builtin_amdgcn_rcpf(fmaf(c0.x, qa0, 1.f)), tA.x);
    tA.y = fmaf(av0, __builtin_amdgcn_rcpf(fmaf(c0.y, qa0, 1.f)), tA.y);
    tB.x = fmaf(av0, __builtin_amdgcn_rcpf(fmaf(c0.x, qb0, 1.f)), tB.x);
    tB.y = fmaf(av0, __builtin_amdgcn_rcpf(fmaf(c0.y, qb0, 1.f)), tB.y);

    tA.x = fmaf(av1, __builtin_amdgcn_rcpf(fmaf(c1.x, qa1, 1.f)), tA.x);
    tA.y = fmaf(av1, __builtin_amdgcn_rcpf(fmaf(c1.y, qa1, 1.f)), tA.y);
    tB.x = fmaf(av1, __builtin_amdgcn_rcpf(fmaf(c1.x, qb1, 1.f)), tB.x);
    tB.y = fmaf(av1, __builtin_amdgcn_rcpf(fmaf(c1.y, qb1, 1.f)), tB.y);

    tA.x = fmaf(av2, __builtin_amdgcn_rcpf(fmaf(c2.x, qa2, 1.f)), tA.x);
    tA.y = fmaf(av2, __builtin_amdgcn_rcpf(fmaf(c2.y, qa2, 1.f)), tA.y);
    tB.x = fmaf(av2, __builtin_amdgcn_rcpf(fmaf(c2.x, qb2, 1.f)), tB.x);
    tB.y = fmaf(av2, __builtin_amdgcn_rcpf(fmaf(c2.y, qb2, 1.f)), tB.y);

    tA.x = fmaf(av3, __builtin_amdgcn_rcpf(fmaf(c3.x, qa3, 1.f)), tA.x);
    tA.y = fmaf(av3, __builtin_amdgcn_rcpf(fmaf(c3.y, qa3, 1.f)), tA.y);
    tB.x = fmaf(av3, __builtin_amdgcn_rcpf(fmaf(c3.x, qb3, 1.f)), tB.x);
    tB.y = fmaf(av3, __builtin_amdgcn_rcpf(fmaf(c3.y, qb3, 1.f)), tB.y);

    c0 = n0; c1 = n1; c2 = n2; c3 = n3;
  }

  int2 mk = *(const int2*)(mask + b * TV + v0);
  float mkx = (1.f - (float)mk.x) * NEG_BIG_F;
  float mky = (1.f - (float)mk.y) * NEG_BIG_F;
  float2 sA, sB;
  sA.x = sumV - 2.f * tA.x + mkx;
  sA.y = sumV - 2.f * tA.y + mky;
  sB.x = sumV - 2.f * tB.x + mkx;
  sB.y = sumV - 2.f * tB.y + mky;

  float mA = fmaxf(sA.x, sA.y);
  float mB = fmaxf(sB.x, sB.y);
  for (int off = 32; off > 0; off >>= 1) {
    mA = fmaxf(mA, __shfl_down(mA, off, 64));
    mB = fmaxf(mB, __shfl_down(mB, off, 64));
  }
  int w = tid >> 6;
  if ((tid & 63) == 0) { redA[w] = mA; redB[w] = mB; }
  __syncthreads();
  if (tid == 0) {
    float a = redA[0], bm = redB[0];
#pragma unroll
    for (int i = 1; i < 8; ++i) { a = fmaxf(a, redA[i]); bm = fmaxf(bm, redB[i]); }
    bc[0] = a; bc[1] = bm;
  }
  __syncthreads();
  float MA = bc[0], MB = bc[1];

  float2 eAv, eBv;
  eAv.x = __builtin_amdgcn_exp2f((sA.x - MA) * LOG2E);
  eAv.y = __builtin_amdgcn_exp2f((sA.y - MA) * LOG2E);
  eBv.x = __builtin_amdgcn_exp2f((sB.x - MB) * LOG2E);
  eBv.y = __builtin_amdgcn_exp2f((sB.y - MB) * LOG2E);
  float lA = eAv.x + eAv.y;
  float lB = eBv.x + eBv.y;
  for (int off = 32; off > 0; off >>= 1) {
    lA += __shfl_down(lA, off, 64);
    lB += __shfl_down(lB, off, 64);
  }
  __syncthreads();   // protect red[] before rewrite
  if ((tid & 63) == 0) { redA[w] = lA; redB[w] = lB; }
  __syncthreads();
  if (tid == 0) {
    float a = 0.f, bs = 0.f;
#pragma unroll
    for (int i = 0; i < 8; ++i) { a += redA[i]; bs += redB[i]; }
    bc[2] = a; bc[3] = bs;
  }
  __syncthreads();
  float iA = 1.f / bc[2];
  float iB = 1.f / bc[3];

  *(float2*)(attn + (size_t)r0 * TV + v0) =
      make_float2(eAv.x * iA, eAv.y * iA);
  *(float2*)(attn + (size_t)(r0 + 1) * TV + v0) =
      make_float2(eBv.x * iB, eBv.y * iB);
}

// ---------------------------------------------------------------------------
// out[b,q,:] = sum_v attn[b,q,v] * inputs[b,v,:]   -- NO ATOMICS.
// Round-11 pv kernel, XCD-SWIZZLED 1-D block map: g = blk&15 -> b = g&3,
// dt = g>>2 (XCD blk&7 then holds b=k&3, dt in {k>>2, k>>2+2}: 2 x 512KB
// X-slices, L2-resident); qt = blk>>4. 512 blocks x 512 thr -> 16 waves/CU.
// 8 waves own disjoint 128-v chunks; partials reduced through 32 KB LDS.
// ---------------------------------------------------------------------------
__global__ __launch_bounds__(512, 4) void pv_kernel(
    const float* __restrict__ attn, const float* __restrict__ X,
    float* __restrict__ out) {
  __shared__ float lds[8 * 1024];    // 32 KB: attn tile, then 8 partial tiles
  int gsl = blockIdx.x & 15;         // (b, dt) slice group
  int b   = gsl & 3;
  int dt  = gsl >> 2;                // 0..3, d-slice of 128
  int qt  = blockIdx.x >> 4;         // 0..31
  int q0  = b * TQ + qt * 8;         // global row (b*TQ + q)
  int tid  = threadIdx.x;
  int w    = tid >> 6;               // wave 0..7 -> v range [w*128, w*128+128)
  int lane = tid & 63;
  int col  = lane & 31;              // float4 d-column
  int qh   = lane >> 5;              // 0..1 -> q rows qh*4 .. qh*4+3
  int d0 = dt * 128 + col * 4;

  // stage attn tile: 8 rows x 1024 v (float4, coalesced)
  {
    const float4* src = (const float4*)(attn + (size_t)q0 * TV);
    float4* dst = (float4*)lds;
    for (int i = tid; i < 8 * 256; i += 512) dst[i] = src[i];
  }
  __syncthreads();

  float4 acc[4];
#pragma unroll
  for (int j = 0; j < 4; ++j) acc[j] = make_float4(0.f, 0.f, 0.f, 0.f);

  int vbase = w * 128;
  const float* Xb = X + ((size_t)b * TV + vbase) * D + d0;
  const float* arow = &lds[(qh * 4) * 1024 + vbase];  // 4 rows, stride 1024

  float4 xc0 = *(const float4*)(Xb + (size_t)0 * D);
  float4 xc1 = *(const float4*)(Xb + (size_t)1 * D);
  float4 xc2 = *(const float4*)(Xb + (size_t)2 * D);
  float4 xc3 = *(const float4*)(Xb + (size_t)3 * D);

  for (int vi = 0; vi < 128; vi += 4) {
    float4 xn0, xn1, xn2, xn3;
    if (vi < 124) {
      const float* Xn = Xb + (size_t)(vi + 4) * D;
      xn0 = *(const float4*)(Xn + (size_t)0 * D);
      xn1 = *(const float4*)(Xn + (size_t)1 * D);
      xn2 = *(const float4*)(Xn + (size_t)2 * D);
      xn3 = *(const float4*)(Xn + (size_t)3 * D);
    }
#pragma unroll
    for (int j = 0; j < 4; ++j) {
      float4 av = *(const float4*)(arow + j * 1024 + vi);  // 2-addr bcast
      acc[j].x = fmaf(av.x, xc0.x, acc[j].x);
      acc[j].y = fmaf(av.x, xc0.y, acc[j].y);
      acc[j].z = fmaf(av.x, xc0.z, acc[j].z);
      acc[j].w = fmaf(av.x, xc0.w, acc[j].w);
      acc[j].x = fmaf(av.y, xc1.x, acc[j].x);
      acc[j].y = fmaf(av.y, xc1.y, acc[j].y);
      acc[j].z = fmaf(av.y, xc1.z, acc[j].z);
      acc[j].w = fmaf(av.y, xc1.w, acc[j].w);
      acc[j].x = fmaf(av.z, xc2.x, acc[j].x);
      acc[j].y = fmaf(av.z, xc2.y, acc[j].y);
      acc[j].z = fmaf(av.z, xc2.z, acc[j].z);
      acc[j].w = fmaf(av.z, xc2.w, acc[j].w);
      acc[j].x = fmaf(av.w, xc3.x, acc[j].x);
      acc[j].y = fmaf(av.w, xc3.y, acc[j].y);
      acc[j].z = fmaf(av.w, xc3.z, acc[j].z);
      acc[j].w = fmaf(av.w, xc3.w, acc[j].w);
    }
    xc0 = xn0; xc1 = xn1; xc2 = xn2; xc3 = xn3;
  }

  __syncthreads();   // everyone done READING the attn tile

  // write wave partials: lds[w][8 rows][32 float4 cols]
  {
    float4* pat = (float4*)lds + (size_t)w * 256;
#pragma unroll
    for (int j = 0; j < 4; ++j)
      pat[(qh * 4 + j) * 32 + col] = acc[j];
  }
  __syncthreads();

  // reduce 8 partials and store: 256 float4 outputs
  if (tid < 256) {
    int row = tid >> 5;            // 0..7
    int c   = tid & 31;            // 0..31
    const float4* p = (const float4*)lds + tid;  // == row*32 + c
    float4 r = p[0];
#pragma unroll
    for (int i = 1; i < 8; ++i) {
      float4 t = p[(size_t)i * 256];
      r.x += t.x; r.y += t.y; r.z += t.z; r.w += t.w;
    }
    *(float4*)(out + (size_t)(q0 + row) * D + dt * 128 + c * 4) = r;
  }
}

extern "C" void kernel_launch(void* const* d_in, const int* in_sizes, int n_in,
                              void* d_out, int out_size, void* d_ws, size_t ws_size,
                              hipStream_t stream) {
  const float* inputs  = (const float*)d_in[0];  // [B,TV,D]
  const float* context = (const float*)d_in[1];  // [B,TQ,D]
  const int*   mask    = (const int*)d_in[2];    // [B,TV]
  const float* Wk      = (const float*)d_in[3];  // [D,A]
  const float* bk      = (const float*)d_in[4];  // [A]
  const float* Wq      = (const float*)d_in[5];  // [D,A]
  const float* bq      = (const float*)d_in[6];  // [A]
  const float* attn_v  = (const float*)d_in[7];  // [A]
  float* out = (float*)d_out;                    // [B,TQ,D]

  // Workspace layout (fp32): Eq | EkT | attn  = 0.5MB + 2MB + 4MB
  float* Eq   = (float*)d_ws;             // [B*TQ, A]
  float* EkT  = Eq + B * TQ * A;          // [B, A, TV]  (transposed!)
  float* attn = EkT + (size_t)B * A * TV; // [B*TQ, TV]

  proj_exp_kernel<<<QBLK + KBLK, 256, 0, stream>>>(context, inputs, Wq, bq,
                                                   Wk, bk, Eq, EkT);
  score_softmax_kernel<<<B * TQ / 2, 512, 0, stream>>>(Eq, EkT, attn_v, mask,
                                                       attn);
  pv_kernel<<<512, 512, 0, stream>>>(attn, inputs, out);
}